// Round 5
// baseline (220.495 us; speedup 1.0000x reference)
//
#include <hip/hip_runtime.h>

// out[b,s,d] = sum_hw feats[b,d,h,w] * masks[s,h,w]
// masks piecewise-constant on 3x3 rect grid (bands [0,9) [9,19) [19,28) both axes)
// => out[b,s,d] = sum_{r<9} w[s][r] * rect[b,d][r]
//
// R4: split into two stream-pure kernels via rect[131072][9] in d_ws (4.7 MB):
//   K1: pure read stream (411 MB), no LDS, no barriers, regs + 4-lane shuffle.
//   K2: pure write stream (66 MB), rect slice cached in LDS->regs, 512B-line stores.

#define NS 126
#define NR 9
#define RECT_BYTES (131072ull * NR * 4ull)

// ---------------- K1: feats -> rect ----------------
__global__ __launch_bounds__(256) void rect_kernel(
    const float* __restrict__ feats, float* __restrict__ rect)
{
    const int tau = blockIdx.x * 256 + threadIdx.x;  // 524288 quarter-image tasks
    const int img = tau >> 2;                        // flat b*512+d
    const int q   = tau & 3;                         // row quarter (rows 7q..7q+6)

    const float4* src = reinterpret_cast<const float4*>(feats)
                      + (size_t)img * 196 + q * 49;

    float a0 = 0.f, a1 = 0.f, a2 = 0.f,
          a3 = 0.f, a4 = 0.f, a5 = 0.f,
          a6 = 0.f, a7 = 0.f, a8 = 0.f;

    #pragma unroll
    for (int i = 0; i < 7; ++i) {
        const float4 v0 = src[7 * i + 0], v1 = src[7 * i + 1], v2 = src[7 * i + 2],
                     v3 = src[7 * i + 3], v4 = src[7 * i + 4], v5 = src[7 * i + 5],
                     v6 = src[7 * i + 6];
        // w bands: [0,9) [9,19) [19,28)
        const float s0 = v0.x + v0.y + v0.z + v0.w + v1.x + v1.y + v1.z + v1.w + v2.x;
        const float s1 = v2.y + v2.z + v2.w + v3.x + v3.y + v3.z + v3.w + v4.x + v4.y + v4.z;
        const float s2 = v4.w + v5.x + v5.y + v5.z + v5.w + v6.x + v6.y + v6.z + v6.w;
        // h band: branchless predication (q is runtime; keep indices static)
        const int   h  = q * 7 + i;
        const float f0 = (h < 9)            ? 1.f : 0.f;
        const float f1 = (h >= 9 && h < 19) ? 1.f : 0.f;
        const float f2 = (h >= 19)          ? 1.f : 0.f;
        a0 += f0 * s0; a1 += f0 * s1; a2 += f0 * s2;
        a3 += f1 * s0; a4 += f1 * s1; a5 += f1 * s2;
        a6 += f2 * s0; a7 += f2 * s1; a8 += f2 * s2;
    }

    // combine the 4 quarter-partials within each 4-lane group (butterfly)
    a0 += __shfl_xor(a0, 1); a1 += __shfl_xor(a1, 1); a2 += __shfl_xor(a2, 1);
    a3 += __shfl_xor(a3, 1); a4 += __shfl_xor(a4, 1); a5 += __shfl_xor(a5, 1);
    a6 += __shfl_xor(a6, 1); a7 += __shfl_xor(a7, 1); a8 += __shfl_xor(a8, 1);
    a0 += __shfl_xor(a0, 2); a1 += __shfl_xor(a1, 2); a2 += __shfl_xor(a2, 2);
    a3 += __shfl_xor(a3, 2); a4 += __shfl_xor(a4, 2); a5 += __shfl_xor(a5, 2);
    a6 += __shfl_xor(a6, 2); a7 += __shfl_xor(a7, 2); a8 += __shfl_xor(a8, 2);

    if (q == 0) {
        float* dst = rect + (size_t)img * NR;
        dst[0] = a0; dst[1] = a1; dst[2] = a2;
        dst[3] = a3; dst[4] = a4; dst[5] = a5;
        dst[6] = a6; dst[7] = a7; dst[8] = a8;
    }
}

// ---------------- K2: rect -> out ----------------
__global__ __launch_bounds__(256) void out_kernel(
    const float* __restrict__ rect, const float* __restrict__ masks,
    float* __restrict__ out)
{
    __shared__ float rect_raw[128 * NR];   // this block's 128 channels x 9
    __shared__ float wtab[NS * NR];

    const int t  = threadIdx.x;
    const int b  = blockIdx.x >> 2;
    const int d0 = (blockIdx.x & 3) << 7;  // 128-channel slice

    // load rect slice (1152 floats = 288 float4, contiguous & 16B-aligned)
    {
        const float4* rsrc = reinterpret_cast<const float4*>(
            rect + ((size_t)b * 512 + d0) * NR);
        float4* rdst = reinterpret_cast<float4*>(rect_raw);
        rdst[t < 256 ? t : t] = rsrc[t];           // t in [0,256)
        if (t < 32) rdst[t + 256] = rsrc[t + 256];
    }
    // weight table (sample one interior pixel per rect)
    for (int i = t; i < NS * NR; i += 256) {
        const int s  = i / NR;
        const int r  = i - s * NR;
        const int bi = r / 3, bj = r - bi * 3;
        const int yc = (bi == 0) ? 4 : ((bi == 1) ? 14 : 23);
        const int xc = (bj == 0) ? 4 : ((bj == 1) ? 14 : 23);
        wtab[i] = masks[s * 784 + yc * 28 + xc];
    }
    __syncthreads();

    // transpose this thread's 4 channels into registers (static indices)
    const int c4 = (t & 31) * 4;
    float4 rv[NR];
    #pragma unroll
    for (int r = 0; r < NR; ++r) {
        rv[r].x = rect_raw[(c4 + 0) * NR + r];
        rv[r].y = rect_raw[(c4 + 1) * NR + r];
        rv[r].z = rect_raw[(c4 + 2) * NR + r];
        rv[r].w = rect_raw[(c4 + 3) * NR + r];
    }

    // stream 126 slot-rows: full 512B-line stores per slot
    const int s_base = t >> 5;
    #pragma unroll
    for (int k = 0; k < 16; ++k) {
        const int s = s_base + (k << 3);
        if (s < NS) {
            float4 a; a.x = a.y = a.z = a.w = 0.f;
            #pragma unroll
            for (int r = 0; r < NR; ++r) {
                const float w = wtab[s * NR + r];
                a.x += w * rv[r].x; a.y += w * rv[r].y;
                a.z += w * rv[r].z; a.w += w * rv[r].w;
            }
            *reinterpret_cast<float4*>(
                out + ((size_t)(b * NS + s) * 512 + d0 + c4)) = a;
        }
    }
}

// ---------------- fallback: R3 fused kernel (used only if ws too small) ----------------
#define BLOCK 256
#define G     16
#define GC    8
#define F4C   (GC * 196)

__global__ void slots_fused(
    const float* __restrict__ feats, const float* __restrict__ masks,
    float* __restrict__ out)
{
    __shared__ float4 buf[F4C];
    __shared__ float  rs[G * 28 * 3];
    __shared__ float  rect_t[NR * G];
    __shared__ float  wtab[NS * NR];

    const int t        = threadIdx.x;
    const int img_base = blockIdx.x * G;
    const int b        = img_base >> 9;
    const int d0       = img_base & 511;

    for (int i = t; i < NS * NR; i += BLOCK) {
        const int s  = i / NR;
        const int r  = i - s * NR;
        const int bi = r / 3, bj = r - bi * 3;
        const int yc = (bi == 0) ? 4 : ((bi == 1) ? 14 : 23);
        const int xc = (bj == 0) ? 4 : ((bj == 1) ? 14 : 23);
        wtab[i] = masks[s * 784 + yc * 28 + xc];
    }
    for (int c = 0; c < 2; ++c) {
        const float4* src = reinterpret_cast<const float4*>(feats)
                          + (size_t)(img_base + c * GC) * 196;
        #pragma unroll
        for (int k = 0; k < 6; ++k) buf[t + k * 256] = src[t + k * 256];
        if (t < 32) buf[t + 1536] = src[t + 1536];
        __syncthreads();
        if (t < GC * 28) {
            const float4* p = &buf[t * 7];
            float4 v0 = p[0], v1 = p[1], v2 = p[2], v3 = p[3],
                   v4 = p[4], v5 = p[5], v6 = p[6];
            float s0 = v0.x + v0.y + v0.z + v0.w + v1.x + v1.y + v1.z + v1.w + v2.x;
            float s1 = v2.y + v2.z + v2.w + v3.x + v3.y + v3.z + v3.w + v4.x + v4.y + v4.z;
            float s2 = v4.w + v5.x + v5.y + v5.z + v5.w + v6.x + v6.y + v6.z + v6.w;
            const int R = c * 224 + t;
            rs[R * 3 + 0] = s0; rs[R * 3 + 1] = s1; rs[R * 3 + 2] = s2;
        }
        __syncthreads();
    }
    if (t < G * NR) {
        const int g  = t / NR, r = t - g * NR;
        const int bi = r / 3, bj = r - bi * 3;
        const int h0 = (bi == 0) ? 0 : ((bi == 1) ? 9 : 19);
        const int h1 = (bi == 0) ? 9 : ((bi == 1) ? 19 : 28);
        float a = 0.f;
        for (int h = h0; h < h1; ++h) a += rs[(g * 28 + h) * 3 + bj];
        rect_t[r * G + g] = a;
    }
    __syncthreads();
    float* outb = out + (size_t)b * NS * 512 + d0;
    for (int i = t; i < (NS * G) / 4; i += BLOCK) {
        const int s  = i >> 2;
        const int c4 = (i & 3) * 4;
        const float* wp = &wtab[s * NR];
        float4 a; a.x = a.y = a.z = a.w = 0.f;
        #pragma unroll
        for (int r = 0; r < NR; ++r) {
            const float  w  = wp[r];
            const float4 rv = *reinterpret_cast<const float4*>(&rect_t[r * G + c4]);
            a.x += w * rv.x; a.y += w * rv.y; a.z += w * rv.z; a.w += w * rv.w;
        }
        *reinterpret_cast<float4*>(&outb[(size_t)s * 512 + c4]) = a;
    }
}

extern "C" void kernel_launch(void* const* d_in, const int* in_sizes, int n_in,
                              void* d_out, int out_size, void* d_ws, size_t ws_size,
                              hipStream_t stream) {
    const float* feats = (const float*)d_in[0];   // (256, 512, 28, 28) f32
    const float* masks = (const float*)d_in[1];   // (126, 28, 28)      f32
    float* out = (float*)d_out;                   // (256, 126, 512)    f32

    if (ws_size >= RECT_BYTES) {
        float* rect = (float*)d_ws;               // (131072, 9) f32
        rect_kernel<<<2048, 256, 0, stream>>>(feats, rect);
        out_kernel <<<1024, 256, 0, stream>>>(rect, masks, out);
    } else {
        slots_fused<<<(256 * 512) / G, BLOCK, 0, stream>>>(feats, masks, out);
    }
}

// Round 6
// 105.064 us; speedup vs baseline: 2.0987x; 2.0987x over previous
//
#include <hip/hip_runtime.h>

// out[b,s,d] = sum_hw feats[b,d,h,w] * masks[s,h,w]
// masks piecewise-constant on 3x3 rect grid (bands [0,9) [9,19) [19,28) both axes)
// => out[b,s,d] = sum_{r<9} w[s][r] * rect[b,d][r]
//
// R5: fused kernel, double-buffered LDS staging via global_load_lds (async,
// lane-linear => matches the intrinsic's wave-uniform-base + lane*16 dest),
// 2-phase pipeline: issue chunk c+1 loads, then compute chunk c. The only
// vmcnt drain is the next __syncthreads, one compute phase later.

#define BLOCK 256
#define G     64          // images (flat b*512+d) per block
#define GC    8           // images per chunk
#define NCH   (G / GC)    // 8 chunks
#define F4C   (GC * 196)  // 1568 float4 per chunk
#define NS    126
#define NR    9

__device__ __forceinline__ void gload_lds16(const float4* g, float4* l) {
    __builtin_amdgcn_global_load_lds(
        (const __attribute__((address_space(1))) void*)g,
        (__attribute__((address_space(3))) void*)l, 16, 0, 0);
}

__global__ __launch_bounds__(BLOCK, 2) void slots_kernel(
    const float* __restrict__ feats,
    const float* __restrict__ masks,
    float* __restrict__ out)
{
    __shared__ float4 buf[2][F4C];       // 50,176 B double-buffered staging
    __shared__ float  rs[G * 28 * 3];    // 21,504 B per-row band sums
    __shared__ float  rect_t[NR * G];    //  2,304 B [r][g]
    __shared__ float  wtab[NS * NR];     //  4,536 B

    const int t        = threadIdx.x;
    const int img_base = blockIdx.x * G;
    const int b        = img_base >> 9;     // / 512
    const int d0       = img_base & 511;

    const float4* fbase = reinterpret_cast<const float4*>(feats)
                        + (size_t)img_base * 196;
    const int wbase = t & ~63;              // wave-uniform lane-block base

    // ---- prologue: stage chunk 0 (async), then wtab while it flies ----
    {
        const float4* src = fbase;
        #pragma unroll
        for (int k = 0; k < 6; ++k)
            gload_lds16(src + k * 256 + t, &buf[0][k * 256 + wbase]);
        if (t < 32)
            gload_lds16(src + 1536 + t, &buf[0][1536]);
    }
    for (int i = t; i < NS * NR; i += BLOCK) {
        const int s  = i / NR;
        const int r  = i - s * NR;
        const int bi = r / 3, bj = r - bi * 3;
        const int yc = (bi == 0) ? 4 : ((bi == 1) ? 14 : 23);
        const int xc = (bj == 0) ? 4 : ((bj == 1) ? 14 : 23);
        wtab[i] = masks[s * 784 + yc * 28 + xc];
    }

    // ---- main loop: barrier; issue stage(c+1); compute rowsums(c) ----
    for (int c = 0; c < NCH; ++c) {
        __syncthreads();                    // buf[c&1] landed; buf[(c+1)&1] free
        if (c + 1 < NCH) {
            const float4* src = fbase + (size_t)(c + 1) * F4C;
            float4* dst = buf[(c + 1) & 1];
            #pragma unroll
            for (int k = 0; k < 6; ++k)
                gload_lds16(src + k * 256 + t, dst + k * 256 + wbase);
            if (t < 32)
                gload_lds16(src + 1536 + t, dst + 1536);
        }
        if (t < GC * 28) {                  // 224 rows this chunk
            const float4* p = &buf[c & 1][t * 7];
            float4 v0 = p[0], v1 = p[1], v2 = p[2], v3 = p[3],
                   v4 = p[4], v5 = p[5], v6 = p[6];
            float s0 = v0.x + v0.y + v0.z + v0.w + v1.x + v1.y + v1.z + v1.w + v2.x;
            float s1 = v2.y + v2.z + v2.w + v3.x + v3.y + v3.z + v3.w + v4.x + v4.y + v4.z;
            float s2 = v4.w + v5.x + v5.y + v5.z + v5.w + v6.x + v6.y + v6.z + v6.w;
            const int R = c * 224 + t;      // == g*28 + h globally
            rs[R * 3 + 0] = s0;
            rs[R * 3 + 1] = s1;
            rs[R * 3 + 2] = s2;
        }
    }
    __syncthreads();

    // ---- rect sums: 64 images x 9 rects (strided loop: 576 > 256!) ----
    for (int i = t; i < G * NR; i += BLOCK) {
        const int g  = i / NR, r = i - (i / NR) * NR;
        const int bi = r / 3, bj = r - bi * 3;
        const int h0 = (bi == 0) ? 0 : ((bi == 1) ? 9 : 19);
        const int h1 = (bi == 0) ? 9 : ((bi == 1) ? 19 : 28);
        float a = 0.f;
        for (int h = h0; h < h1; ++h)
            a += rs[(g * 28 + h) * 3 + bj];
        rect_t[r * G + g] = a;
    }
    __syncthreads();

    // ---- outputs: 126 slots x 64 channels, 256B contiguous per 16 lanes ----
    float* outb = out + (size_t)b * NS * 512 + d0;
    for (int i = t; i < (NS * G) / 4; i += BLOCK) {   // 2016 float4 tasks
        const int s  = i >> 4;
        const int c4 = (i & 15) << 2;
        const float* wp = &wtab[s * NR];
        float4 a; a.x = a.y = a.z = a.w = 0.f;
        #pragma unroll
        for (int r = 0; r < NR; ++r) {
            const float  w  = wp[r];
            const float4 rv = *reinterpret_cast<const float4*>(&rect_t[r * G + c4]);
            a.x += w * rv.x; a.y += w * rv.y; a.z += w * rv.z; a.w += w * rv.w;
        }
        *reinterpret_cast<float4*>(&outb[(size_t)s * 512 + c4]) = a;
    }
}

extern "C" void kernel_launch(void* const* d_in, const int* in_sizes, int n_in,
                              void* d_out, int out_size, void* d_ws, size_t ws_size,
                              hipStream_t stream) {
    const float* feats = (const float*)d_in[0];   // (256, 512, 28, 28) f32
    const float* masks = (const float*)d_in[1];   // (126, 28, 28)      f32
    float* out = (float*)d_out;                   // (256, 126, 512)    f32

    const int blocks = (256 * 512) / G;           // 2048
    slots_kernel<<<blocks, BLOCK, 0, stream>>>(feats, masks, out);
}

// Round 7
// 85.760 us; speedup vs baseline: 2.5711x; 1.2251x over previous
//
#include <hip/hip_runtime.h>

// out[b,s,d] = sum_hw feats[b,d,h,w] * masks[s,h,w]
// masks piecewise-constant on 3x3 rect grid (bands [0,9) [9,19) [19,28) both axes)
// => out[b,s,d] = sum_{r<9} w[s][r] * rect[b,d][r]
//
// R6 = R5 (best, 105.06 us) + non-temporal cache policy on the two streams:
//   - feats loads: global_load_lds with aux=NT (one-touch stream; don't churn L2)
//   - out stores:  __builtin_nontemporal_store (write-once; no write-allocate)
// Everything else identical to R5.

#define BLOCK 256
#define G     64          // images (flat b*512+d) per block
#define GC    8           // images per chunk
#define NCH   (G / GC)    // 8 chunks
#define F4C   (GC * 196)  // 1568 float4 per chunk
#define NS    126
#define NR    9

typedef float f32x4 __attribute__((ext_vector_type(4)));

// aux=2 -> NT cache-policy bit on gfx950 (CPol: sc0=1, nt=2, sc1=16).
// NT only affects allocation/retention, never values: safe.
__device__ __forceinline__ void gload_lds16_nt(const float4* g, float4* l) {
    __builtin_amdgcn_global_load_lds(
        (const __attribute__((address_space(1))) void*)g,
        (__attribute__((address_space(3))) void*)l, 16, 0, 2);
}

__global__ __launch_bounds__(BLOCK, 2) void slots_kernel(
    const float* __restrict__ feats,
    const float* __restrict__ masks,
    float* __restrict__ out)
{
    __shared__ float4 buf[2][F4C];       // 50,176 B double-buffered staging
    __shared__ float  rs[G * 28 * 3];    // 21,504 B per-row band sums
    __shared__ float  rect_t[NR * G];    //  2,304 B [r][g]
    __shared__ float  wtab[NS * NR];     //  4,536 B

    const int t        = threadIdx.x;
    const int img_base = blockIdx.x * G;
    const int b        = img_base >> 9;     // / 512
    const int d0       = img_base & 511;

    const float4* fbase = reinterpret_cast<const float4*>(feats)
                        + (size_t)img_base * 196;
    const int wbase = t & ~63;              // wave-uniform lane-block base

    // ---- prologue: stage chunk 0 (async NT), then wtab while it flies ----
    {
        const float4* src = fbase;
        #pragma unroll
        for (int k = 0; k < 6; ++k)
            gload_lds16_nt(src + k * 256 + t, &buf[0][k * 256 + wbase]);
        if (t < 32)
            gload_lds16_nt(src + 1536 + t, &buf[0][1536]);
    }
    for (int i = t; i < NS * NR; i += BLOCK) {
        const int s  = i / NR;
        const int r  = i - s * NR;
        const int bi = r / 3, bj = r - bi * 3;
        const int yc = (bi == 0) ? 4 : ((bi == 1) ? 14 : 23);
        const int xc = (bj == 0) ? 4 : ((bj == 1) ? 14 : 23);
        wtab[i] = masks[s * 784 + yc * 28 + xc];   // masks reused chip-wide: keep cached
    }

    // ---- main loop: barrier; issue stage(c+1); compute rowsums(c) ----
    for (int c = 0; c < NCH; ++c) {
        __syncthreads();                    // buf[c&1] landed; buf[(c+1)&1] free
        if (c + 1 < NCH) {
            const float4* src = fbase + (size_t)(c + 1) * F4C;
            float4* dst = buf[(c + 1) & 1];
            #pragma unroll
            for (int k = 0; k < 6; ++k)
                gload_lds16_nt(src + k * 256 + t, dst + k * 256 + wbase);
            if (t < 32)
                gload_lds16_nt(src + 1536 + t, dst + 1536);
        }
        if (t < GC * 28) {                  // 224 rows this chunk
            const float4* p = &buf[c & 1][t * 7];
            float4 v0 = p[0], v1 = p[1], v2 = p[2], v3 = p[3],
                   v4 = p[4], v5 = p[5], v6 = p[6];
            float s0 = v0.x + v0.y + v0.z + v0.w + v1.x + v1.y + v1.z + v1.w + v2.x;
            float s1 = v2.y + v2.z + v2.w + v3.x + v3.y + v3.z + v3.w + v4.x + v4.y + v4.z;
            float s2 = v4.w + v5.x + v5.y + v5.z + v5.w + v6.x + v6.y + v6.z + v6.w;
            const int R = c * 224 + t;      // == g*28 + h globally
            rs[R * 3 + 0] = s0;
            rs[R * 3 + 1] = s1;
            rs[R * 3 + 2] = s2;
        }
    }
    __syncthreads();

    // ---- rect sums: 64 images x 9 rects (strided loop: 576 > 256) ----
    for (int i = t; i < G * NR; i += BLOCK) {
        const int g  = i / NR, r = i - (i / NR) * NR;
        const int bi = r / 3, bj = r - bi * 3;
        const int h0 = (bi == 0) ? 0 : ((bi == 1) ? 9 : 19);
        const int h1 = (bi == 0) ? 9 : ((bi == 1) ? 19 : 28);
        float a = 0.f;
        for (int h = h0; h < h1; ++h)
            a += rs[(g * 28 + h) * 3 + bj];
        rect_t[r * G + g] = a;
    }
    __syncthreads();

    // ---- outputs: 126 slots x 64 channels, NT float4 stores ----
    float* outb = out + (size_t)b * NS * 512 + d0;
    for (int i = t; i < (NS * G) / 4; i += BLOCK) {   // 2016 float4 tasks
        const int s  = i >> 4;
        const int c4 = (i & 15) << 2;
        const float* wp = &wtab[s * NR];
        f32x4 a = {0.f, 0.f, 0.f, 0.f};
        #pragma unroll
        for (int r = 0; r < NR; ++r) {
            const f32x4 rv = *reinterpret_cast<const f32x4*>(&rect_t[r * G + c4]);
            a += wp[r] * rv;
        }
        __builtin_nontemporal_store(
            a, reinterpret_cast<f32x4*>(&outb[(size_t)s * 512 + c4]));
    }
}

extern "C" void kernel_launch(void* const* d_in, const int* in_sizes, int n_in,
                              void* d_out, int out_size, void* d_ws, size_t ws_size,
                              hipStream_t stream) {
    const float* feats = (const float*)d_in[0];   // (256, 512, 28, 28) f32
    const float* masks = (const float*)d_in[1];   // (126, 28, 28)      f32
    float* out = (float*)d_out;                   // (256, 126, 512)    f32

    const int blocks = (256 * 512) / G;           // 2048
    slots_kernel<<<blocks, BLOCK, 0, stream>>>(feats, masks, out);
}

// Round 8
// 85.318 us; speedup vs baseline: 2.5844x; 1.0052x over previous
//
#include <hip/hip_runtime.h>

// out[b,s,d] = sum_hw feats[b,d,h,w] * masks[s,h,w]
// masks piecewise-constant on 3x3 rect grid (bands [0,9) [9,19) [19,28) both axes)
// => out[b,s,d] = sum_{r<9} w[s][r] * rect[b,d][r]
//
// R7 = R6 (NT streams, async dbuf global_load_lds) with a smaller footprint:
//   GC=4 images/chunk (buf 25 KB), rect reduction folded into the pipeline
//   (reduce chunk c-1 while chunk c computes, chunk c+1 in flight),
//   rs double-buffered per-chunk (2.7 KB). LDS 33.5 KB -> 4 blocks/CU.

#define BLOCK 256
#define G     32          // images (flat b*512+d) per block
#define GC    4           // images per chunk
#define NCH   (G / GC)    // 8 chunks
#define F4C   (GC * 196)  // 784 float4 per chunk
#define NS    126
#define NR    9

typedef float f32x4 __attribute__((ext_vector_type(4)));

// aux=2 -> NT cache-policy bit on gfx950. Allocation hint only; values exact.
__device__ __forceinline__ void gload_lds16_nt(const float4* g, float4* l) {
    __builtin_amdgcn_global_load_lds(
        (const __attribute__((address_space(1))) void*)g,
        (__attribute__((address_space(3))) void*)l, 16, 0, 2);
}

__global__ __launch_bounds__(BLOCK, 4) void slots_kernel(
    const float* __restrict__ feats,
    const float* __restrict__ masks,
    float* __restrict__ out)
{
    __shared__ float4 buf[2][F4C];        // 25,088 B staging (double-buffered)
    __shared__ float  rs[2][GC * 28 * 3]; //  2,688 B per-chunk row band sums
    __shared__ float  rect_t[NR * G];     //  1,152 B [r][g]
    __shared__ float  wtab[NS * NR];      //  4,536 B

    const int t        = threadIdx.x;
    const int img_base = blockIdx.x * G;
    const int b        = img_base >> 9;     // / 512
    const int d0       = img_base & 511;

    const float4* fbase = reinterpret_cast<const float4*>(feats)
                        + (size_t)img_base * 196;
    const int wbase = t & ~63;              // wave-uniform lane-block base

    // ---- prologue: stage chunk 0 (async NT); wtab while it flies ----
    {
        const float4* src = fbase;
        #pragma unroll
        for (int k = 0; k < 3; ++k)
            gload_lds16_nt(src + k * 256 + t, &buf[0][k * 256 + wbase]);
        if (t < 16)
            gload_lds16_nt(src + 768 + t, &buf[0][768]);
    }
    for (int i = t; i < NS * NR; i += BLOCK) {
        const int s  = i / NR;
        const int r  = i - s * NR;
        const int bi = r / 3, bj = r - bi * 3;
        const int yc = (bi == 0) ? 4 : ((bi == 1) ? 14 : 23);
        const int xc = (bj == 0) ? 4 : ((bj == 1) ? 14 : 23);
        wtab[i] = masks[s * 784 + yc * 28 + xc];   // masks reused chip-wide: cached
    }

    // ---- pipeline: barrier; issue c+1; reduce c-1; row-sums c ----
    for (int c = 0; c < NCH; ++c) {
        __syncthreads();   // buf[c&1] landed; rs[(c-1)&1] complete; buf[(c+1)&1] free
        if (c + 1 < NCH) {
            const float4* src = fbase + (size_t)(c + 1) * F4C;
            float4* dst = buf[(c + 1) & 1];
            #pragma unroll
            for (int k = 0; k < 3; ++k)
                gload_lds16_nt(src + k * 256 + t, dst + k * 256 + wbase);
            if (t < 16)
                gload_lds16_nt(src + 768 + t, dst + 768);
        }
        if (c >= 1 && t >= 128 && t < 128 + GC * NR) {   // 36 reduce tasks (wave 2)
            const int i  = t - 128;
            const int gl = i / NR, r = i - gl * NR;
            const int bi = r / 3, bj = r - bi * 3;
            const int h0 = (bi == 0) ? 0 : ((bi == 1) ? 9 : 19);
            const int h1 = (bi == 0) ? 9 : ((bi == 1) ? 19 : 28);
            const float* rsp = rs[(c - 1) & 1];
            float a = 0.f;
            for (int h = h0; h < h1; ++h)
                a += rsp[(gl * 28 + h) * 3 + bj];
            rect_t[r * G + (c - 1) * GC + gl] = a;
        }
        if (t < GC * 28) {                  // 112 rows this chunk (waves 0-1)
            const float4* p = &buf[c & 1][t * 7];
            float4 v0 = p[0], v1 = p[1], v2 = p[2], v3 = p[3],
                   v4 = p[4], v5 = p[5], v6 = p[6];
            float s0 = v0.x + v0.y + v0.z + v0.w + v1.x + v1.y + v1.z + v1.w + v2.x;
            float s1 = v2.y + v2.z + v2.w + v3.x + v3.y + v3.z + v3.w + v4.x + v4.y + v4.z;
            float s2 = v4.w + v5.x + v5.y + v5.z + v5.w + v6.x + v6.y + v6.z + v6.w;
            float* rsp = rs[c & 1];
            rsp[t * 3 + 0] = s0;
            rsp[t * 3 + 1] = s1;
            rsp[t * 3 + 2] = s2;
        }
    }
    __syncthreads();

    // ---- last chunk's reduce (36 tasks) ----
    if (t < GC * NR) {
        const int gl = t / NR, r = t - gl * NR;
        const int bi = r / 3, bj = r - bi * 3;
        const int h0 = (bi == 0) ? 0 : ((bi == 1) ? 9 : 19);
        const int h1 = (bi == 0) ? 9 : ((bi == 1) ? 19 : 28);
        const float* rsp = rs[(NCH - 1) & 1];
        float a = 0.f;
        for (int h = h0; h < h1; ++h)
            a += rsp[(gl * 28 + h) * 3 + bj];
        rect_t[r * G + (NCH - 1) * GC + gl] = a;
    }
    __syncthreads();

    // ---- outputs: 126 slots x 32 channels; 128B contiguous per 8 lanes ----
    float* outb = out + (size_t)b * NS * 512 + d0;
    for (int i = t; i < (NS * G) / 4; i += BLOCK) {   // 1008 float4 tasks
        const int s  = i >> 3;
        const int c4 = (i & 7) << 2;
        const float* wp = &wtab[s * NR];
        f32x4 a = {0.f, 0.f, 0.f, 0.f};
        #pragma unroll
        for (int r = 0; r < NR; ++r) {
            const f32x4 rv = *reinterpret_cast<const f32x4*>(&rect_t[r * G + c4]);
            a += wp[r] * rv;
        }
        __builtin_nontemporal_store(
            a, reinterpret_cast<f32x4*>(&outb[(size_t)s * 512 + c4]));
    }
}

extern "C" void kernel_launch(void* const* d_in, const int* in_sizes, int n_in,
                              void* d_out, int out_size, void* d_ws, size_t ws_size,
                              hipStream_t stream) {
    const float* feats = (const float*)d_in[0];   // (256, 512, 28, 28) f32
    const float* masks = (const float*)d_in[1];   // (126, 28, 28)      f32
    float* out = (float*)d_out;                   // (256, 126, 512)    f32

    const int blocks = (256 * 512) / G;           // 4096
    slots_kernel<<<blocks, BLOCK, 0, stream>>>(feats, masks, out);
}